// Round 10
// baseline (149.916 us; speedup 1.0000x reference)
//
#include <hip/hip_runtime.h>
#include <math.h>

// Problem constants (B,T,E,H fixed by setup_inputs).
constexpr int B_ = 8, T_ = 2048, E_ = 1024, H_ = 64;
constexpr long BT = (long)B_ * T_;   // 16384 rows

typedef __attribute__((ext_vector_type(8))) short bf16x8;   // 8 bf16 (4 VGPRs)
typedef __attribute__((ext_vector_type(4))) float f32x4;    // MFMA 16x16 acc

__device__ inline unsigned short bf16_rne(float f) {
    union { float f; unsigned u; } v; v.f = f;
    unsigned u = v.u + (0x7FFFu + ((v.u >> 16) & 1u));
    return (unsigned short)(u >> 16);
}
__device__ inline unsigned pack_bf16x2(float lo, float hi) {
    return (unsigned)bf16_rne(lo) | ((unsigned)bf16_rne(hi) << 16);
}

// Async global->LDS DMA, 16B per lane (qkv kernel only).
__device__ inline void load_lds16(const void* g, void* l) {
    __builtin_amdgcn_global_load_lds(
        (const __attribute__((address_space(1))) void*)(uintptr_t)g,
        (__attribute__((address_space(3))) void*)(unsigned)(uintptr_t)l,
        16, 0, 0);
}

// Inline-asm 16B global load: compiler tracks no vmem value -> emits no
// vmcnt waits; we own the hazards via the tied-operand waits below.
__device__ inline bf16x8 gload16(const unsigned short* p) {
    bf16x8 r;
    asm volatile("global_load_dwordx4 %0, %1, off" : "=v"(r) : "v"(p));
    return r;
}

constexpr float QS = 0.18033688011112042f;   // H^-0.5 * log2(e), folded into Wq

// ====================================================================
// Kernel 0: build B-frag-ready transposed bf16 weight buffer. (R3)
// ====================================================================
__global__ __launch_bounds__(256) void wt_build_k(
    const float* __restrict__ Wk, const float* __restrict__ Wq,
    const float* __restrict__ Wv, unsigned short* __restrict__ Wt)
{
    const int d    = blockIdx.x * 256 + threadIdx.x;   // 0..24575
    const int tile = d >> 6;
    const int lq   = d & 63;
    const int quad = lq >> 4;
    const int l16  = lq & 15;
    const int kc   = tile / 12;
    const int nt   = tile - kc * 12;
    const int n    = nt * 16 + l16;

    const float* src; int col; float s = 1.0f;
    if (n < 64)       { src = Wk; col = n; }
    else if (n < 128) { src = Wq; col = n - 64; s = QS; }
    else              { src = Wv; col = n - 128; }

    const int kk0 = kc * 32 + quad * 8;
    const float* sp = src + (size_t)kk0 * H_ + col;
    unsigned p[4];
    #pragma unroll
    for (int jj = 0; jj < 4; jj++)
        p[jj] = pack_bf16x2(sp[(2 * jj) * H_] * s, sp[(2 * jj + 1) * H_] * s);
    *(uint4*)(Wt + (size_t)d * 8) = make_uint4(p[0], p[1], p[2], p[3]);
}

// ====================================================================
// Kernel 1: MFMA QKV projection, R7 core (DMA-staged x). Only change:
// Vf key permutation now matches the transposed-QK attention kernel:
// position p = q*8+j -> key = (j<4) ? q*4+j : 16 + q*4 + (j-4).
// ====================================================================
__global__ __launch_bounds__(512, 4) void qkv_mfma_k(
    const float* __restrict__ x, const unsigned short* __restrict__ Wt,
    unsigned short* __restrict__ kO, unsigned short* __restrict__ qO,
    unsigned short* __restrict__ vfO)
{
    __shared__ float4 xs[2][32][16];        // 16 KB: [buf][row][chunk], swizzled
    __shared__ unsigned short VL[32][66];   // V tile staging (pad 66)

    const int t    = threadIdx.x;           // 0..511
    const int w    = t >> 6;                // 0..7
    const int l    = t & 63;
    const int l16  = l & 15;
    const int quad = l >> 4;
    const int rg   = w >> 2;                // row-group 0..1
    const int nq   = w & 3;                 // n-quarter 0..3 (3 tiles each)
    const int row0 = blockIdx.x * 32 + rg * 16;
    const int row0b = blockIdx.x * 32;

    const int rr = w * 4 + (l >> 4);        // staged row 0..31
    const int cc = l & 15;                  // LDS chunk slot
    const int gg = cc ^ (rr & 7);           // global chunk fetched (swizzle)
    const float* gsrc = x + (size_t)(row0b + rr) * E_ + gg * 4;

    const int r  = rg * 16 + l16;           // A-frag row in tile
    const int rx = r & 7;                   // swizzle key

    f32x4 acc[3];
    #pragma unroll
    for (int n = 0; n < 3; n++) acc[n] = (f32x4){0.f, 0.f, 0.f, 0.f};

    load_lds16(gsrc, &xs[0][rr][cc]);       // stage tile 0

    for (int it = 0; it < 16; ++it) {
        const int buf = it & 1;
        __syncthreads();                    // drains tile-it DMA + prev reads
        if (it + 1 < 16)
            load_lds16(gsrc + (it + 1) * 64, &xs[buf ^ 1][rr][cc]);

        #pragma unroll
        for (int kk = 0; kk < 2; ++kk) {
            const int G0 = kk * 8 + quad * 2;
            float4 fa = xs[buf][r][G0 ^ rx];
            float4 fb = xs[buf][r][(G0 + 1) ^ rx];

            const int kc = it * 2 + kk;
            const unsigned short* wpp = Wt + (size_t)(kc * 12 + nq * 3) * 512 + (size_t)l * 8;
            bf16x8 b0 = *(const bf16x8*)(wpp);
            bf16x8 b1 = *(const bf16x8*)(wpp + 512);
            bf16x8 b2 = *(const bf16x8*)(wpp + 1024);

            union { bf16x8 v; unsigned u[4]; } av;
            av.u[0] = pack_bf16x2(fa.x, fa.y);
            av.u[1] = pack_bf16x2(fa.z, fa.w);
            av.u[2] = pack_bf16x2(fb.x, fb.y);
            av.u[3] = pack_bf16x2(fb.z, fb.w);

            acc[0] = __builtin_amdgcn_mfma_f32_16x16x32_bf16(av.v, b0, acc[0], 0, 0, 0);
            acc[1] = __builtin_amdgcn_mfma_f32_16x16x32_bf16(av.v, b1, acc[1], 0, 0, 0);
            acc[2] = __builtin_amdgcn_mfma_f32_16x16x32_bf16(av.v, b2, acc[2], 0, 0, 0);
        }
    }

    // ---- epilogue part 1: k/q global stores, v -> LDS staging ----
    #pragma unroll
    for (int n = 0; n < 3; n++) {
        const int gn = nq * 3 + n;          // 0..11
        const int hb = gn * 16 + l16;
        if (gn < 4) {
            #pragma unroll
            for (int rr2 = 0; rr2 < 4; rr2++) {
                const int row = row0 + quad * 4 + rr2;
                kO[(size_t)row * H_ + hb] = bf16_rne(acc[n][rr2]);
            }
        } else if (gn < 8) {
            #pragma unroll
            for (int rr2 = 0; rr2 < 4; rr2++) {
                const int row = row0 + quad * 4 + rr2;
                qO[(size_t)row * H_ + (hb - 64)] = bf16_rne(acc[n][rr2]);
            }
        } else {
            #pragma unroll
            for (int rr2 = 0; rr2 < 4; rr2++)
                VL[rg * 16 + quad * 4 + rr2][(gn - 8) * 16 + l16] = bf16_rne(acc[n][rr2]);
        }
    }
    __syncthreads();

    // ---- epilogue part 2: permuted frag gather, coalesced Vf store ----
    // NEW permutation: position p = qf*8+j -> key = j<4 ? qf*4+j
    //                                              : 16+qf*4+(j-4)
    if (t < 256) {
        const int g  = t >> 6;          // h-group 0..3
        const int lf = t & 15;
        const int qf = (t >> 4) & 3;
        unsigned pk[4];
        #pragma unroll
        for (int jj = 0; jj < 4; jj++) {
            const int jb   = 2 * jj;
            const int key0 = (jb < 4) ? (qf * 4 + jb) : (16 + qf * 4 + (jb - 4));
            const int key1 = key0 + 1;
            pk[jj] = (unsigned)VL[key0][g * 16 + lf]
                   | ((unsigned)VL[key1][g * 16 + lf] << 16);
        }
        const int tile = blockIdx.x;    // = b*64 + kt
        *(uint4*)(vfO + ((size_t)tile * 4 + g) * 512 + (size_t)(t & 63) * 8) =
            make_uint4(pk[0], pk[1], pk[2], pk[3]);
    }
}

// ====================================================================
// Kernel 2: MFMA flash attention, R10: TRANSPOSED QK (S^T = K·Q^T via
// operand swap) -> P lands with query=l16, keys=quad*4+r, which IS the
// PV A-operand lane mapping: P packs fully in-lane. NO LDS in the loop
// (no P round-trip, no lgkmcnt). All VMEM via inline asm + manual
// vmcnt: K double-buffered (A/B sets), V single set re-issued after
// its PV MFMAs (load latency >> MFMA source read). Waits: vmcnt(8)
// before QK (drains K(i)), vmcnt(4) before PV (drains V(i)).
// ~110 live VGPRs under the 128 cap (R9 post-mortem: pressure at the
// cap caused allocator copies of in-flight regs -> corruption).
// ====================================================================
#define ISSUE_K(kt, K0, K1, K2, K3) do {                                     \
    const unsigned short* _kp = kbp + (size_t)((kt) * 32 + l16) * H_ + quad * 8; \
    K0 = gload16(_kp);                                                       \
    K1 = gload16(_kp + 32);                                                  \
    K2 = gload16(_kp + 16 * H_);                                             \
    K3 = gload16(_kp + 16 * H_ + 32);                                        \
} while (0)

#define ISSUE_V(kt) do {                                                     \
    const unsigned short* _vp = vfb + (size_t)(kt) * 2048 + l * 8;           \
    V0 = gload16(_vp);                                                       \
    V1 = gload16(_vp + 512);                                                 \
    V2 = gload16(_vp + 1024);                                                \
    V3 = gload16(_vp + 1536);                                                \
} while (0)

#define WAITK(K0, K1, K2, K3)                                                \
    asm volatile("s_waitcnt vmcnt(8)"                                        \
        : "+v"(K0), "+v"(K1), "+v"(K2), "+v"(K3) : : "memory")

#define WAITV()                                                              \
    asm volatile("s_waitcnt vmcnt(4)"                                        \
        : "+v"(V0), "+v"(V1), "+v"(V2), "+v"(V3) : : "memory")

#define BODYQK(kb, K0, K1, K2, K3) do {                                      \
    s0 = (f32x4){0.f, 0.f, 0.f, 0.f};                                        \
    s1 = (f32x4){0.f, 0.f, 0.f, 0.f};                                        \
    s0 = __builtin_amdgcn_mfma_f32_16x16x32_bf16(K0, aq0, s0, 0, 0, 0);      \
    s0 = __builtin_amdgcn_mfma_f32_16x16x32_bf16(K1, aq1, s0, 0, 0, 0);      \
    s1 = __builtin_amdgcn_mfma_f32_16x16x32_bf16(K2, aq0, s1, 0, 0, 0);      \
    s1 = __builtin_amdgcn_mfma_f32_16x16x32_bf16(K3, aq1, s1, 0, 0, 0);      \
    if ((kb) + 31 > t0) {                                                    \
        const int qrow = t0 + l16;                                           \
        _Pragma("unroll")                                                    \
        for (int r = 0; r < 4; r++) {                                        \
            if ((kb) + quad * 4 + r > qrow)      s0[r] = -3.0e38f;           \
            if ((kb) + 16 + quad * 4 + r > qrow) s1[r] = -3.0e38f;           \
        }                                                                    \
    }                                                                        \
    float p0[4], p1[4];                                                      \
    _Pragma("unroll")                                                        \
    for (int r = 0; r < 4; r++) { p0[r] = exp2f(s0[r]); p1[r] = exp2f(s1[r]); } \
    lsp += (p0[0] + p0[1]) + (p0[2] + p0[3])                                 \
         + (p1[0] + p1[1]) + (p1[2] + p1[3]);                                \
    av.u[0] = pack_bf16x2(p0[0], p0[1]);                                     \
    av.u[1] = pack_bf16x2(p0[2], p0[3]);                                     \
    av.u[2] = pack_bf16x2(p1[0], p1[1]);                                     \
    av.u[3] = pack_bf16x2(p1[2], p1[3]);                                     \
} while (0)

#define BODYPV() do {                                                        \
    o[0] = __builtin_amdgcn_mfma_f32_16x16x32_bf16(av.v, V0, o[0], 0, 0, 0); \
    o[1] = __builtin_amdgcn_mfma_f32_16x16x32_bf16(av.v, V1, o[1], 0, 0, 0); \
    o[2] = __builtin_amdgcn_mfma_f32_16x16x32_bf16(av.v, V2, o[2], 0, 0, 0); \
    o[3] = __builtin_amdgcn_mfma_f32_16x16x32_bf16(av.v, V3, o[3], 0, 0, 0); \
} while (0)

__global__ __launch_bounds__(256, 4) void attn_mfma(
    const unsigned short* __restrict__ q,   // bf16 [B][T][H], pre-scaled
    const unsigned short* __restrict__ k,   // bf16 [B][T][H]
    const unsigned short* __restrict__ vf,  // bf16 fragment-major (new perm)
    float* __restrict__ out)
{
    __shared__ float Ot[4][16][68];             // 17.4 KB merge buffer
    __shared__ float lsW[4][16];

    const int t    = threadIdx.x;
    const int w    = t >> 6;
    const int l    = t & 63;
    const int l16  = l & 15;
    const int quad = l >> 4;

    const int b    = blockIdx.x & 7;
    const int qidx = blockIdx.x >> 3;
    const int qt   = (qidx & 1) ? (127 - (qidx >> 1)) : (qidx >> 1);
    const int t0   = qt * 16;
    const int nk   = t0 / 32 + 1;

    const unsigned short* kbp = k  + (size_t)b * T_ * H_;
    const unsigned short* vfb = vf + (size_t)b * 64 * 2048;

    // Q via asm too (keeps compiler's vmem ledger empty).
    const unsigned short* qp = q + ((size_t)b * T_ + t0 + l16) * H_ + quad * 8;
    bf16x8 aq0 = gload16(qp);
    bf16x8 aq1 = gload16(qp + 32);

    f32x4 o[4];
    #pragma unroll
    for (int g = 0; g < 4; g++) o[g] = (f32x4){0.f, 0.f, 0.f, 0.f};
    float lsp = 0.f;

    bf16x8 A0, A1, A2, A3, B0, B1, B2, B3, V0, V1, V2, V3;
    union { bf16x8 v; unsigned u[4]; } av;
    f32x4 s0, s1;

    int kt = w;
    if (kt < nk) {
        ISSUE_K(kt, A0, A1, A2, A3);            // 4 out (+2 Q = 6)... order: Q,K,V
        ISSUE_V(kt);                            // 10 out total
        asm volatile("s_waitcnt vmcnt(8)" : "+v"(aq0), "+v"(aq1) : : "memory");  // Q done
        while (true) {
            int kn = (kt + 4 < nk) ? kt + 4 : kt;
            ISSUE_K(kn, B0, B1, B2, B3);        // 12 out
            WAITK(A0, A1, A2, A3);              // K(i) done -> 8 out
            BODYQK(kt * 32, A0, A1, A2, A3);
            WAITV();                            // V(i) done -> 4 out
            BODYPV();
            kt += 4; if (kt >= nk) break;
            ISSUE_V(kt);                        // 8 out

            kn = (kt + 4 < nk) ? kt + 4 : kt;
            ISSUE_K(kn, A0, A1, A2, A3);        // 12 out
            WAITK(B0, B1, B2, B3);              // -> 8
            BODYQK(kt * 32, B0, B1, B2, B3);
            WAITV();                            // -> 4
            BODYPV();
            kt += 4; if (kt >= nk) break;
            ISSUE_V(kt);                        // 8 out
        }
    }
    asm volatile("s_waitcnt vmcnt(0)" ::: "memory");   // drain stale prefetch

    // ---- lsum: sum across quads (query = l16 in every quad) ----
    lsp += __shfl_xor(lsp, 16);
    lsp += __shfl_xor(lsp, 32);
    if (l < 16) lsW[w][l] = lsp;

    #pragma unroll
    for (int g = 0; g < 4; g++)
        #pragma unroll
        for (int r = 0; r < 4; r++)
            Ot[w][quad * 4 + r][g * 16 + l16] = o[g][r];
    __syncthreads();

    // ---- merge: all 4 waves, wave w handles h-group w ----
    {
        const int col = w * 16 + l16;
        #pragma unroll
        for (int r = 0; r < 4; r++) {
            const int row = quad * 4 + r;
            float L  = lsW[0][row] + lsW[1][row] + lsW[2][row] + lsW[3][row];
            float sv = Ot[0][row][col] + Ot[1][row][col]
                     + Ot[2][row][col] + Ot[3][row][col];
            out[((size_t)b * T_ + t0 + row) * H_ + col] = sv / L;
        }
    }
}

// ====================================================================
extern "C" void kernel_launch(void* const* d_in, const int* in_sizes, int n_in,
                              void* d_out, int out_size, void* d_ws, size_t ws_size,
                              hipStream_t stream)
{
    const float* x  = (const float*)d_in[0];
    const float* Wk = (const float*)d_in[1];
    const float* Wq = (const float*)d_in[2];
    const float* Wv = (const float*)d_in[3];

    // workspace: Wt (384KB) | k | q | vf (bf16, 2MB each)
    unsigned short* wt    = (unsigned short*)d_ws;
    unsigned short* kbuf  = wt + 24576 * 8;
    unsigned short* qbuf  = kbuf + BT * H_;
    unsigned short* vfbuf = qbuf + BT * H_;
    float* outp = (float*)d_out;

    wt_build_k<<<96, 256, 0, stream>>>(Wk, Wq, Wv, wt);
    qkv_mfma_k<<<(B_ * T_) / 32, 512, 0, stream>>>(x, wt, kbuf, qbuf, vfbuf);
    attn_mfma<<<B_ * 128, 256, 0, stream>>>(qbuf, kbuf, vfbuf, outp);
}